// Round 2
// baseline (1355.410 us; speedup 1.0000x reference)
//
#include <hip/hip_runtime.h>

#define T_TOK 2048
#define HID   2048
#define INTER 768
#define NE    32
#define NSLOT 8192   // T_TOK * TOP_K

typedef short bf16x8 __attribute__((ext_vector_type(8)));
typedef float f32x4  __attribute__((ext_vector_type(4)));

__device__ __forceinline__ unsigned short f2b(float f){
  unsigned u = __builtin_bit_cast(unsigned, f);
  u += 0x7fffu + ((u >> 16) & 1u);      // RNE
  return (unsigned short)(u >> 16);
}
__device__ __forceinline__ unsigned pk2(float a, float b){
  return (unsigned)f2b(a) | ((unsigned)f2b(b) << 16);
}

// ---------------- workspace layout (bytes) ----------------
#define XB_OFF    0ul           // bf16 x  [2048][2048]  = 8388608
#define HBUF_OFF  8388608ul     // bf16 h  [8192][768]   = 12582912
#define TKW_OFF   20971520ul    // f32 topk_w [2048][4]  = 32768
#define TKI_OFF   21004288ul    // i32 topk_i [2048][4]  = 32768
#define ROWS_OFF  21037056ul    // i32 rows [8192]       = 32768
#define WTS_OFF   21069824ul    // f32 wts  [8192]       = 32768
#define OFFS_OFF  21102592ul    // i32 offsets[33] (256B)
#define LOGIT_OFF 21102848ul    // f32 logits [2048][32] = 262144  (zeroed)
#define CNT_OFF   21364992ul    // i32 counts[32]        (zeroed)
#define FILL_OFF  21365120ul    // i32 fill[32]          (zeroed)
#define ZERO_OFF  21102848ul
#define ZERO_SZ   (262144ul + 128ul + 128ul)

// ---------------- x fp32 -> bf16 ----------------
__global__ void convert_x_kernel(const float* __restrict__ x, ushort* __restrict__ xb){
  int i = (blockIdx.x * 256 + threadIdx.x) * 8;
  float4 a = *(const float4*)(x + i);
  float4 b = *(const float4*)(x + i + 4);
  uint4 o;
  o.x = pk2(a.x, a.y);
  o.y = pk2(a.z, a.w);
  o.z = pk2(b.x, b.y);
  o.w = pk2(b.z, b.w);
  *(uint4*)(xb + i) = o;
}

// ---------------- router logits (fp32 GEMM, split-K atomic) ----------------
__global__ void router_gemm(const float* __restrict__ x, const float* __restrict__ wr,
                            float* __restrict__ logits){
  const int tt = blockIdx.x;   // 64 tokens
  const int kb = blockIdx.y;   // 256 k
  __shared__ float xs[64 * 64];
  __shared__ float wsm[64 * 32];
  const int tid = threadIdx.x;
  const int r = tid >> 5, e = tid & 31;
  float acc[8];
#pragma unroll
  for (int i = 0; i < 8; i++) acc[i] = 0.0f;

  for (int sub = 0; sub < 4; ++sub){
    const int k0 = kb * 256 + sub * 64;
    __syncthreads();
#pragma unroll
    for (int j = 0; j < 4; j++){
      int f4 = tid + j * 256;
      int row = f4 >> 4, c4 = f4 & 15;
      float4 v = *(const float4*)(x + (size_t)(tt * 64 + row) * HID + k0 + c4 * 4);
      *(float4*)(xs + row * 64 + c4 * 4) = v;
    }
#pragma unroll
    for (int j = 0; j < 2; j++){
      int f4 = tid + j * 256;
      int row = f4 >> 3, c4 = f4 & 7;
      float4 v = *(const float4*)(wr + (size_t)(k0 + row) * NE + c4 * 4);
      *(float4*)(wsm + row * NE + c4 * 4) = v;
    }
    __syncthreads();
    for (int kk = 0; kk < 64; kk++){
      float wv = wsm[kk * NE + e];
#pragma unroll
      for (int i = 0; i < 8; i++) acc[i] += xs[(r + i * 8) * 64 + kk] * wv;
    }
  }
#pragma unroll
  for (int i = 0; i < 8; i++)
    atomicAdd(&logits[(size_t)(tt * 64 + r + i * 8) * NE + e], acc[i]);
}

// ---------------- softmax + top-4 + renorm + counts ----------------
__global__ void topk_kernel(const float* __restrict__ logits, float* __restrict__ topk_w,
                            int* __restrict__ topk_i, int* __restrict__ counts){
  int t = blockIdx.x * blockDim.x + threadIdx.x;
  if (t >= T_TOK) return;
  float l[32];
  const float4* lp = (const float4*)(logits + (size_t)t * NE);
#pragma unroll
  for (int i = 0; i < 8; i++){
    float4 v = lp[i];
    l[i*4+0] = v.x; l[i*4+1] = v.y; l[i*4+2] = v.z; l[i*4+3] = v.w;
  }
  float m = l[0];
#pragma unroll
  for (int i = 1; i < 32; i++) m = fmaxf(m, l[i]);
#pragma unroll
  for (int i = 0; i < 32; i++) l[i] = __expf(l[i] - m);
  float wsel[4]; int isel[4];
#pragma unroll
  for (int k = 0; k < 4; k++){
    float best = l[0]; int bi = 0;
#pragma unroll
    for (int i = 1; i < 32; i++){ if (l[i] > best){ best = l[i]; bi = i; } }
    wsel[k] = best; isel[k] = bi; l[bi] = -1.0f;
  }
  float s4 = wsel[0] + wsel[1] + wsel[2] + wsel[3];
  float inv = 1.0f / s4;
#pragma unroll
  for (int k = 0; k < 4; k++){
    topk_w[t * 4 + k] = wsel[k] * inv;
    topk_i[t * 4 + k] = isel[k];
    atomicAdd(&counts[isel[k]], 1);
  }
}

__global__ void prefix_kernel(const int* __restrict__ counts, int* __restrict__ offsets){
  if (threadIdx.x == 0){
    int a = 0; offsets[0] = 0;
    for (int e = 0; e < NE; e++){ a += counts[e]; offsets[e + 1] = a; }
  }
}

__global__ void scatter_kernel(const int* __restrict__ topk_i, const float* __restrict__ topk_w,
                               const int* __restrict__ offsets, int* __restrict__ fill,
                               int* __restrict__ rows, float* __restrict__ wts){
  int gid = blockIdx.x * 256 + threadIdx.x;
  int t = gid >> 2;
  int e = topk_i[gid];
  int pos = atomicAdd(&fill[e], 1);
  int s = offsets[e] + pos;
  rows[s] = t;
  wts[s] = topk_w[gid];
}

// ---------------- gate+up GEMM ----------------
// BM=128, BN=64 (x2 matrices), BK=64, 512 threads (8 waves, 4m x 2n), 2-phase
// prefetch, double-buffered swizzled LDS (A[128][64] + Bg[64][64] + Bu[64][64]).
#define NT_GU 32
__global__ __launch_bounds__(512, 4) void gateup_kernel(
    const ushort* __restrict__ xb, const float* __restrict__ wg,
    const float* __restrict__ wu, const int* __restrict__ rows,
    const float* __restrict__ wts, const int* __restrict__ counts,
    const int* __restrict__ offsets, ushort* __restrict__ hbuf)
{
  const int e = blockIdx.z, mt = blockIdx.x, nt = blockIdx.y;
  const int cnt = counts[e];
  if (mt * 128 >= cnt) return;
  const int off = offsets[e];
  const int n0 = nt * 64;

  __shared__ __align__(16) ushort lds[2 * 16384];  // 64 KB

  const int tid = threadIdx.x;

  // stage-role indices
  const int ra = tid >> 2, quad = tid & 3;     // A: one row, 2x16B blocks
  const int srow = mt * 128 + ra;
  const int slotA = off + (srow < cnt ? srow : 0);
  const int tokA = rows[slotA];
  const ushort* agp = xb + (size_t)tokA * HID;
  const int q0 = quad * 2, q1 = q0 + 1;
  const int axk = ra & 7;
  const int adst0 = ra * 64 + (q0 ^ axk) * 8;
  const int adst1 = ra * 64 + (q1 ^ axk) * 8;

  const int bn = tid & 63, kg = tid >> 6;      // B: one col, 8 k's
  const size_t wofs = (size_t)e * (HID * INTER) + n0 + bn;
  const float* wgp = wg + wofs;
  const float* wup = wu + wofs;
  const int bdst = bn * 64 + (kg ^ (bn & 7)) * 8;

  // compute-role indices
  const int lane = tid & 63, wv = tid >> 6;
  const int wm = wv >> 1, wn = wv & 1;
  const int fr = lane & 15, ko = lane >> 4;
  const int fxk = fr & 7;

  f32x4 accg[2][2], accu[2][2];
#pragma unroll
  for (int i = 0; i < 2; i++)
#pragma unroll
    for (int j = 0; j < 2; j++){ accg[i][j] = (f32x4)(0.0f); accu[i][j] = (f32x4)(0.0f); }

  uint4 pa0, pa1;
  float sg[8], su[8];

  // prologue: load + write tile 0
  pa0 = *(const uint4*)(agp + q0 * 8);
  pa1 = *(const uint4*)(agp + q1 * 8);
  {
    const float* pg_ = wgp + (size_t)(kg * 8) * INTER;
    const float* pu_ = wup + (size_t)(kg * 8) * INTER;
#pragma unroll
    for (int kk = 0; kk < 8; kk++){ sg[kk] = pg_[(size_t)kk * INTER]; su[kk] = pu_[(size_t)kk * INTER]; }
  }
  {
    ushort* dA = lds;
    *(uint4*)(dA + adst0) = pa0;
    *(uint4*)(dA + adst1) = pa1;
    uint4 pg, pu;
    pg.x = pk2(sg[0], sg[1]); pg.y = pk2(sg[2], sg[3]);
    pg.z = pk2(sg[4], sg[5]); pg.w = pk2(sg[6], sg[7]);
    pu.x = pk2(su[0], su[1]); pu.y = pk2(su[2], su[3]);
    pu.z = pk2(su[4], su[5]); pu.w = pk2(su[6], su[7]);
    *(uint4*)(dA + 8192 + bdst) = pg;
    *(uint4*)(dA + 12288 + bdst) = pu;
  }
  __syncthreads();

  int cbase = 0;
  for (int t = 0; t < NT_GU; ++t){
    const int nb = cbase ^ 16384;
    // issue next tile's global loads early
    if (t + 1 < NT_GU){
      const int k0 = (t + 1) * 64;
      pa0 = *(const uint4*)(agp + k0 + q0 * 8);
      pa1 = *(const uint4*)(agp + k0 + q1 * 8);
      const float* pg_ = wgp + (size_t)(k0 + kg * 8) * INTER;
      const float* pu_ = wup + (size_t)(k0 + kg * 8) * INTER;
#pragma unroll
      for (int kk = 0; kk < 8; kk++){ sg[kk] = pg_[(size_t)kk * INTER]; su[kk] = pu_[(size_t)kk * INTER]; }
    }
    // compute current tile
    const ushort* A  = lds + cbase;
    const ushort* BG = lds + cbase + 8192;
    const ushort* BU = lds + cbase + 12288;
#pragma unroll
    for (int kk = 0; kk < 2; kk++){
      const int bsel = ((kk * 4 + ko) ^ fxk) * 8;
      bf16x8 a[2], bg2[2], bu2[2];
#pragma unroll
      for (int mf = 0; mf < 2; mf++)
        a[mf] = *(const bf16x8*)(A + (wm * 32 + mf * 16 + fr) * 64 + bsel);
#pragma unroll
      for (int nf = 0; nf < 2; nf++){
        bg2[nf] = *(const bf16x8*)(BG + (wn * 32 + nf * 16 + fr) * 64 + bsel);
        bu2[nf] = *(const bf16x8*)(BU + (wn * 32 + nf * 16 + fr) * 64 + bsel);
      }
#pragma unroll
      for (int mf = 0; mf < 2; mf++)
#pragma unroll
        for (int nf = 0; nf < 2; nf++){
          accg[mf][nf] = __builtin_amdgcn_mfma_f32_16x16x32_bf16(a[mf], bg2[nf], accg[mf][nf], 0, 0, 0);
          accu[mf][nf] = __builtin_amdgcn_mfma_f32_16x16x32_bf16(a[mf], bu2[nf], accu[mf][nf], 0, 0, 0);
        }
    }
    // write staged tile
    if (t + 1 < NT_GU){
      ushort* dA = lds + nb;
      *(uint4*)(dA + adst0) = pa0;
      *(uint4*)(dA + adst1) = pa1;
      uint4 pg, pu;
      pg.x = pk2(sg[0], sg[1]); pg.y = pk2(sg[2], sg[3]);
      pg.z = pk2(sg[4], sg[5]); pg.w = pk2(sg[6], sg[7]);
      pu.x = pk2(su[0], su[1]); pu.y = pk2(su[2], su[3]);
      pu.z = pk2(su[4], su[5]); pu.w = pk2(su[6], su[7]);
      *(uint4*)(dA + 8192 + bdst) = pg;
      *(uint4*)(dA + 12288 + bdst) = pu;
    }
    __syncthreads();
    cbase = nb;
  }

  // epilogue
#pragma unroll
  for (int mf = 0; mf < 2; mf++)
#pragma unroll
    for (int j = 0; j < 4; j++){
      int rl = wm * 32 + mf * 16 + ko * 4 + j;
      int gr = mt * 128 + rl;
      if (gr < cnt){
        float w = wts[off + gr];
        size_t robase = (size_t)(off + gr) * INTER + n0;
#pragma unroll
        for (int nf = 0; nf < 2; nf++){
          float g = accg[mf][nf][j], u = accu[mf][nf][j];
          float h = (g / (1.0f + __expf(-g))) * u * w;
          hbuf[robase + wn * 32 + nf * 16 + fr] = f2b(h);
        }
      }
    }
}

// ---------------- down GEMM: out[tok] += h @ wd ----------------
#define NT_DN 12
__global__ __launch_bounds__(512, 4) void down_kernel(
    const ushort* __restrict__ hbuf, const float* __restrict__ wd,
    const int* __restrict__ rows, const int* __restrict__ counts,
    const int* __restrict__ offsets, float* __restrict__ out)
{
  const int e = blockIdx.z, mt = blockIdx.x, nt = blockIdx.y;
  const int cnt = counts[e];
  if (mt * 128 >= cnt) return;
  const int off = offsets[e];
  const int n0 = nt * 64;

  __shared__ __align__(16) ushort lds[2 * 12288];  // 48 KB

  const int tid = threadIdx.x;

  const int ra = tid >> 2, quad = tid & 3;
  const int srow = mt * 128 + ra;
  const int slotA = off + (srow < cnt ? srow : 0);
  const ushort* agp = hbuf + (size_t)slotA * INTER;
  const int q0 = quad * 2, q1 = q0 + 1;
  const int axk = ra & 7;
  const int adst0 = ra * 64 + (q0 ^ axk) * 8;
  const int adst1 = ra * 64 + (q1 ^ axk) * 8;

  const int bn = tid & 63, kg = tid >> 6;
  const float* wdp = wd + (size_t)e * (INTER * HID) + n0 + bn;
  const int bdst = bn * 64 + (kg ^ (bn & 7)) * 8;

  const int lane = tid & 63, wv = tid >> 6;
  const int wm = wv >> 1, wn = wv & 1;
  const int fr = lane & 15, ko = lane >> 4;
  const int fxk = fr & 7;

  f32x4 acc[2][2];
#pragma unroll
  for (int i = 0; i < 2; i++)
#pragma unroll
    for (int j = 0; j < 2; j++) acc[i][j] = (f32x4)(0.0f);

  uint4 pa0, pa1;
  float sb[8];

  pa0 = *(const uint4*)(agp + q0 * 8);
  pa1 = *(const uint4*)(agp + q1 * 8);
  {
    const float* p = wdp + (size_t)(kg * 8) * HID;
#pragma unroll
    for (int kk = 0; kk < 8; kk++) sb[kk] = p[(size_t)kk * HID];
  }
  {
    ushort* dA = lds;
    *(uint4*)(dA + adst0) = pa0;
    *(uint4*)(dA + adst1) = pa1;
    uint4 pb;
    pb.x = pk2(sb[0], sb[1]); pb.y = pk2(sb[2], sb[3]);
    pb.z = pk2(sb[4], sb[5]); pb.w = pk2(sb[6], sb[7]);
    *(uint4*)(dA + 8192 + bdst) = pb;
  }
  __syncthreads();

  int cbase = 0;
  for (int t = 0; t < NT_DN; ++t){
    const int nb = cbase ^ 12288;
    if (t + 1 < NT_DN){
      const int k0 = (t + 1) * 64;
      pa0 = *(const uint4*)(agp + k0 + q0 * 8);
      pa1 = *(const uint4*)(agp + k0 + q1 * 8);
      const float* p = wdp + (size_t)(k0 + kg * 8) * HID;
#pragma unroll
      for (int kk = 0; kk < 8; kk++) sb[kk] = p[(size_t)kk * HID];
    }
    const ushort* A = lds + cbase;
    const ushort* B = lds + cbase + 8192;
#pragma unroll
    for (int kk = 0; kk < 2; kk++){
      const int bsel = ((kk * 4 + ko) ^ fxk) * 8;
      bf16x8 a[2], b2[2];
#pragma unroll
      for (int mf = 0; mf < 2; mf++)
        a[mf] = *(const bf16x8*)(A + (wm * 32 + mf * 16 + fr) * 64 + bsel);
#pragma unroll
      for (int nf = 0; nf < 2; nf++)
        b2[nf] = *(const bf16x8*)(B + (wn * 32 + nf * 16 + fr) * 64 + bsel);
#pragma unroll
      for (int mf = 0; mf < 2; mf++)
#pragma unroll
        for (int nf = 0; nf < 2; nf++)
          acc[mf][nf] = __builtin_amdgcn_mfma_f32_16x16x32_bf16(a[mf], b2[nf], acc[mf][nf], 0, 0, 0);
    }
    if (t + 1 < NT_DN){
      ushort* dA = lds + nb;
      *(uint4*)(dA + adst0) = pa0;
      *(uint4*)(dA + adst1) = pa1;
      uint4 pb;
      pb.x = pk2(sb[0], sb[1]); pb.y = pk2(sb[2], sb[3]);
      pb.z = pk2(sb[4], sb[5]); pb.w = pk2(sb[6], sb[7]);
      *(uint4*)(dA + 8192 + bdst) = pb;
    }
    __syncthreads();
    cbase = nb;
  }

#pragma unroll
  for (int mf = 0; mf < 2; mf++)
#pragma unroll
    for (int j = 0; j < 4; j++){
      int rl = wm * 32 + mf * 16 + ko * 4 + j;
      int gr = mt * 128 + rl;
      if (gr < cnt){
        int tok = rows[off + gr];
        float* obase = out + (size_t)tok * HID + n0;
#pragma unroll
        for (int nf = 0; nf < 2; nf++)
          atomicAdd(obase + wn * 32 + nf * 16 + fr, acc[mf][nf][j]);
      }
    }
}

// ---------------- launch ----------------
extern "C" void kernel_launch(void* const* d_in, const int* in_sizes, int n_in,
                              void* d_out, int out_size, void* d_ws, size_t ws_size,
                              hipStream_t stream){
  const float* x  = (const float*)d_in[0];
  const float* wr = (const float*)d_in[1];
  const float* wg = (const float*)d_in[2];
  const float* wu = (const float*)d_in[3];
  const float* wd = (const float*)d_in[4];
  float* out = (float*)d_out;
  char* ws = (char*)d_ws;

  ushort* xb     = (ushort*)(ws + XB_OFF);
  ushort* hbuf   = (ushort*)(ws + HBUF_OFF);
  float*  topkw  = (float*)(ws + TKW_OFF);
  int*    topki  = (int*)(ws + TKI_OFF);
  int*    rows   = (int*)(ws + ROWS_OFF);
  float*  wts    = (float*)(ws + WTS_OFF);
  int*    offs   = (int*)(ws + OFFS_OFF);
  float*  logits = (float*)(ws + LOGIT_OFF);
  int*    counts = (int*)(ws + CNT_OFF);
  int*    fill   = (int*)(ws + FILL_OFF);

  hipMemsetAsync(ws + ZERO_OFF, 0, ZERO_SZ, stream);
  hipMemsetAsync(d_out, 0, (size_t)out_size * sizeof(float), stream);

  convert_x_kernel<<<2048, 256, 0, stream>>>(x, xb);
  router_gemm<<<dim3(32, 8), 256, 0, stream>>>(x, wr, logits);
  topk_kernel<<<8, 256, 0, stream>>>(logits, topkw, topki, counts);
  prefix_kernel<<<1, 64, 0, stream>>>(counts, offs);
  scatter_kernel<<<32, 256, 0, stream>>>(topki, topkw, offs, fill, rows, wts);
  gateup_kernel<<<dim3(16, 12, 32), 512, 0, stream>>>(xb, wg, wu, rows, wts, counts, offs, hbuf);
  down_kernel<<<dim3(16, 32, 32), 512, 0, stream>>>(hbuf, wd, rows, counts, offs, out);
}

// Round 3
// 347.736 us; speedup vs baseline: 3.8978x; 3.8978x over previous
//
#include <hip/hip_runtime.h>

#define T_TOK 2048
#define HID   2048
#define INTER 768
#define NE    32
#define NSLOT 8192   // T_TOK * TOP_K
#define MAXT  96     // max (expert, mt) tiles at BM=128: sum ceil(cnt/128) < 64+32

typedef short bf16x8 __attribute__((ext_vector_type(8)));
typedef float f32x4  __attribute__((ext_vector_type(4)));

__device__ __forceinline__ unsigned short f2b(float f){
  unsigned u = __builtin_bit_cast(unsigned, f);
  u += 0x7fffu + ((u >> 16) & 1u);      // RNE
  return (unsigned short)(u >> 16);
}
__device__ __forceinline__ unsigned pk2(float a, float b){
  return (unsigned)f2b(a) | ((unsigned)f2b(b) << 16);
}

// ---------------- workspace layout (bytes) ----------------
#define XB_OFF    0ul           // bf16 x  [2048][2048]  = 8388608
#define HBUF_OFF  8388608ul     // bf16 h  [8192][768]   = 12582912
#define TKW_OFF   20971520ul    // f32 topk_w [2048][4]  = 32768
#define TKI_OFF   21004288ul    // i32 topk_i [2048][4]  = 32768
#define ROWS_OFF  21037056ul    // i32 rows [8192]       = 32768
#define WTS_OFF   21069824ul    // f32 wts  [8192]       = 32768
#define OFFS_OFF  21102592ul    // i32 offsets[33] (256B)
#define LOGIT_OFF 21102848ul    // f32 logits [2048][32] = 262144  (zeroed)
#define CNT_OFF   21364992ul    // i32 counts[32]        (zeroed)
#define FILL_OFF  21365120ul    // i32 fill[32]          (zeroed)
#define TLIST_OFF 21365248ul    // i32 tlist[96] (512B, fully written by prefix)
#define ZERO_OFF  21102848ul
#define ZERO_SZ   (262144ul + 128ul + 128ul)

// ---------------- x fp32 -> bf16 ----------------
__global__ void convert_x_kernel(const float* __restrict__ x, ushort* __restrict__ xb){
  int i = (blockIdx.x * 256 + threadIdx.x) * 8;
  float4 a = *(const float4*)(x + i);
  float4 b = *(const float4*)(x + i + 4);
  uint4 o;
  o.x = pk2(a.x, a.y);
  o.y = pk2(a.z, a.w);
  o.z = pk2(b.x, b.y);
  o.w = pk2(b.z, b.w);
  *(uint4*)(xb + i) = o;
}

// ---------------- router logits (fp32 GEMM, split-K atomic) ----------------
__global__ void router_gemm(const float* __restrict__ x, const float* __restrict__ wr,
                            float* __restrict__ logits){
  const int tt = blockIdx.x;   // 64 tokens
  const int kb = blockIdx.y;   // 256 k
  __shared__ float xs[64 * 64];
  __shared__ float wsm[64 * 32];
  const int tid = threadIdx.x;
  const int r = tid >> 5, e = tid & 31;
  float acc[8];
#pragma unroll
  for (int i = 0; i < 8; i++) acc[i] = 0.0f;

  for (int sub = 0; sub < 4; ++sub){
    const int k0 = kb * 256 + sub * 64;
    __syncthreads();
#pragma unroll
    for (int j = 0; j < 4; j++){
      int f4 = tid + j * 256;
      int row = f4 >> 4, c4 = f4 & 15;
      float4 v = *(const float4*)(x + (size_t)(tt * 64 + row) * HID + k0 + c4 * 4);
      *(float4*)(xs + row * 64 + c4 * 4) = v;
    }
#pragma unroll
    for (int j = 0; j < 2; j++){
      int f4 = tid + j * 256;
      int row = f4 >> 3, c4 = f4 & 7;
      float4 v = *(const float4*)(wr + (size_t)(k0 + row) * NE + c4 * 4);
      *(float4*)(wsm + row * NE + c4 * 4) = v;
    }
    __syncthreads();
    for (int kk = 0; kk < 64; kk++){
      float wv = wsm[kk * NE + e];
#pragma unroll
      for (int i = 0; i < 8; i++) acc[i] += xs[(r + i * 8) * 64 + kk] * wv;
    }
  }
#pragma unroll
  for (int i = 0; i < 8; i++)
    atomicAdd(&logits[(size_t)(tt * 64 + r + i * 8) * NE + e], acc[i]);
}

// ---------------- softmax + top-4 + renorm + counts ----------------
__global__ void topk_kernel(const float* __restrict__ logits, float* __restrict__ topk_w,
                            int* __restrict__ topk_i, int* __restrict__ counts){
  int t = blockIdx.x * blockDim.x + threadIdx.x;
  if (t >= T_TOK) return;
  float l[32];
  const float4* lp = (const float4*)(logits + (size_t)t * NE);
#pragma unroll
  for (int i = 0; i < 8; i++){
    float4 v = lp[i];
    l[i*4+0] = v.x; l[i*4+1] = v.y; l[i*4+2] = v.z; l[i*4+3] = v.w;
  }
  float m = l[0];
#pragma unroll
  for (int i = 1; i < 32; i++) m = fmaxf(m, l[i]);
#pragma unroll
  for (int i = 0; i < 32; i++) l[i] = __expf(l[i] - m);
  float wsel[4]; int isel[4];
#pragma unroll
  for (int k = 0; k < 4; k++){
    float best = l[0]; int bi = 0;
#pragma unroll
    for (int i = 1; i < 32; i++){ if (l[i] > best){ best = l[i]; bi = i; } }
    wsel[k] = best; isel[k] = bi; l[bi] = -1.0f;
  }
  float s4 = wsel[0] + wsel[1] + wsel[2] + wsel[3];
  float inv = 1.0f / s4;
#pragma unroll
  for (int k = 0; k < 4; k++){
    topk_w[t * 4 + k] = wsel[k] * inv;
    topk_i[t * 4 + k] = isel[k];
    atomicAdd(&counts[isel[k]], 1);
  }
}

// prefix sum + compacted (expert, mt) tile list so active GEMM blocks are
// contiguous and first in dispatch order (round-2 lesson: strided-active
// grids cluster on a CU subset -> 6.8% occupancy).
__global__ void prefix_kernel(const int* __restrict__ counts, int* __restrict__ offsets,
                              int* __restrict__ tlist){
  if (threadIdx.x == 0){
    int a = 0; offsets[0] = 0; int nt_ = 0;
    for (int e = 0; e < NE; e++){
      int c = counts[e];
      for (int m = 0; m * 128 < c && nt_ < MAXT; m++) tlist[nt_++] = e | (m << 16);
      a += c; offsets[e + 1] = a;
    }
    for (; nt_ < MAXT; nt_++) tlist[nt_] = -1;
  }
}

__global__ void scatter_kernel(const int* __restrict__ topk_i, const float* __restrict__ topk_w,
                               const int* __restrict__ offsets, int* __restrict__ fill,
                               int* __restrict__ rows, float* __restrict__ wts){
  int gid = blockIdx.x * 256 + threadIdx.x;
  int t = gid >> 2;
  int e = topk_i[gid];
  int pos = atomicAdd(&fill[e], 1);
  int s = offsets[e] + pos;
  rows[s] = t;
  wts[s] = topk_w[gid];
}

// ---------------- gate+up GEMM ----------------
// BM=128, BN=64 (x2 matrices), BK=64, 512 threads (8 waves, 4m x 2n), 2-phase
// prefetch, double-buffered swizzled LDS. grid = (nt=12, tile=96), tile list
// compacted so all active blocks are contiguous in dispatch order.
#define NT_GU 32
__global__ __launch_bounds__(512, 2) void gateup_kernel(
    const ushort* __restrict__ xb, const float* __restrict__ wg,
    const float* __restrict__ wu, const int* __restrict__ rows,
    const float* __restrict__ wts, const int* __restrict__ counts,
    const int* __restrict__ offsets, const int* __restrict__ tlist,
    ushort* __restrict__ hbuf)
{
  const int w = tlist[blockIdx.y];
  if (w < 0) return;
  const int e = w & 0xffff, mt = w >> 16;
  const int nt = blockIdx.x;
  const int cnt = counts[e];
  const int off = offsets[e];
  const int n0 = nt * 64;

  __shared__ __align__(16) ushort lds[2 * 16384];  // 64 KB

  const int tid = threadIdx.x;

  // stage-role indices
  const int ra = tid >> 2, quad = tid & 3;     // A: one row, 2x16B blocks
  const int srow = mt * 128 + ra;
  const int slotA = off + (srow < cnt ? srow : 0);
  const int tokA = rows[slotA];
  const ushort* agp = xb + (size_t)tokA * HID;
  const int q0 = quad * 2, q1 = q0 + 1;
  const int axk = ra & 7;
  const int adst0 = ra * 64 + (q0 ^ axk) * 8;
  const int adst1 = ra * 64 + (q1 ^ axk) * 8;

  const int bn = tid & 63, kg = tid >> 6;      // B: one col, 8 k's
  const size_t wofs = (size_t)e * (HID * INTER) + n0 + bn;
  const float* wgp = wg + wofs;
  const float* wup = wu + wofs;
  const int bdst = bn * 64 + (kg ^ (bn & 7)) * 8;

  // compute-role indices
  const int lane = tid & 63, wv = tid >> 6;
  const int wm = wv >> 1, wn = wv & 1;
  const int fr = lane & 15, ko = lane >> 4;
  const int fxk = fr & 7;

  f32x4 accg[2][2], accu[2][2];
#pragma unroll
  for (int i = 0; i < 2; i++)
#pragma unroll
    for (int j = 0; j < 2; j++){ accg[i][j] = (f32x4)(0.0f); accu[i][j] = (f32x4)(0.0f); }

  uint4 pa0, pa1;
  float sg[8], su[8];

  // prologue: load + write tile 0
  pa0 = *(const uint4*)(agp + q0 * 8);
  pa1 = *(const uint4*)(agp + q1 * 8);
  {
    const float* pg_ = wgp + (size_t)(kg * 8) * INTER;
    const float* pu_ = wup + (size_t)(kg * 8) * INTER;
#pragma unroll
    for (int kk = 0; kk < 8; kk++){ sg[kk] = pg_[(size_t)kk * INTER]; su[kk] = pu_[(size_t)kk * INTER]; }
  }
  {
    ushort* dA = lds;
    *(uint4*)(dA + adst0) = pa0;
    *(uint4*)(dA + adst1) = pa1;
    uint4 pg, pu;
    pg.x = pk2(sg[0], sg[1]); pg.y = pk2(sg[2], sg[3]);
    pg.z = pk2(sg[4], sg[5]); pg.w = pk2(sg[6], sg[7]);
    pu.x = pk2(su[0], su[1]); pu.y = pk2(su[2], su[3]);
    pu.z = pk2(su[4], su[5]); pu.w = pk2(su[6], su[7]);
    *(uint4*)(dA + 8192 + bdst) = pg;
    *(uint4*)(dA + 12288 + bdst) = pu;
  }
  __syncthreads();

  int cbase = 0;
  for (int t = 0; t < NT_GU; ++t){
    const int nb = cbase ^ 16384;
    // issue next tile's global loads early
    if (t + 1 < NT_GU){
      const int k0 = (t + 1) * 64;
      pa0 = *(const uint4*)(agp + k0 + q0 * 8);
      pa1 = *(const uint4*)(agp + k0 + q1 * 8);
      const float* pg_ = wgp + (size_t)(k0 + kg * 8) * INTER;
      const float* pu_ = wup + (size_t)(k0 + kg * 8) * INTER;
#pragma unroll
      for (int kk = 0; kk < 8; kk++){ sg[kk] = pg_[(size_t)kk * INTER]; su[kk] = pu_[(size_t)kk * INTER]; }
    }
    // compute current tile
    const ushort* A  = lds + cbase;
    const ushort* BG = lds + cbase + 8192;
    const ushort* BU = lds + cbase + 12288;
#pragma unroll
    for (int kk = 0; kk < 2; kk++){
      const int bsel = ((kk * 4 + ko) ^ fxk) * 8;
      bf16x8 a[2], bg2[2], bu2[2];
#pragma unroll
      for (int mf = 0; mf < 2; mf++)
        a[mf] = *(const bf16x8*)(A + (wm * 32 + mf * 16 + fr) * 64 + bsel);
#pragma unroll
      for (int nf = 0; nf < 2; nf++){
        bg2[nf] = *(const bf16x8*)(BG + (wn * 32 + nf * 16 + fr) * 64 + bsel);
        bu2[nf] = *(const bf16x8*)(BU + (wn * 32 + nf * 16 + fr) * 64 + bsel);
      }
#pragma unroll
      for (int mf = 0; mf < 2; mf++)
#pragma unroll
        for (int nf = 0; nf < 2; nf++){
          accg[mf][nf] = __builtin_amdgcn_mfma_f32_16x16x32_bf16(a[mf], bg2[nf], accg[mf][nf], 0, 0, 0);
          accu[mf][nf] = __builtin_amdgcn_mfma_f32_16x16x32_bf16(a[mf], bu2[nf], accu[mf][nf], 0, 0, 0);
        }
    }
    // write staged tile
    if (t + 1 < NT_GU){
      ushort* dA = lds + nb;
      *(uint4*)(dA + adst0) = pa0;
      *(uint4*)(dA + adst1) = pa1;
      uint4 pg, pu;
      pg.x = pk2(sg[0], sg[1]); pg.y = pk2(sg[2], sg[3]);
      pg.z = pk2(sg[4], sg[5]); pg.w = pk2(sg[6], sg[7]);
      pu.x = pk2(su[0], su[1]); pu.y = pk2(su[2], su[3]);
      pu.z = pk2(su[4], su[5]); pu.w = pk2(su[6], su[7]);
      *(uint4*)(dA + 8192 + bdst) = pg;
      *(uint4*)(dA + 12288 + bdst) = pu;
    }
    __syncthreads();
    cbase = nb;
  }

  // epilogue
#pragma unroll
  for (int mf = 0; mf < 2; mf++)
#pragma unroll
    for (int j = 0; j < 4; j++){
      int rl = wm * 32 + mf * 16 + ko * 4 + j;
      int gr = mt * 128 + rl;
      if (gr < cnt){
        float w2 = wts[off + gr];
        size_t robase = (size_t)(off + gr) * INTER + n0;
#pragma unroll
        for (int nf = 0; nf < 2; nf++){
          float g = accg[mf][nf][j], u = accu[mf][nf][j];
          float h = (g / (1.0f + __expf(-g))) * u * w2;
          hbuf[robase + wn * 32 + nf * 16 + fr] = f2b(h);
        }
      }
    }
}

// ---------------- down GEMM: out[tok] += h @ wd ----------------
#define NT_DN 12
__global__ __launch_bounds__(512, 2) void down_kernel(
    const ushort* __restrict__ hbuf, const float* __restrict__ wd,
    const int* __restrict__ rows, const int* __restrict__ counts,
    const int* __restrict__ offsets, const int* __restrict__ tlist,
    float* __restrict__ out)
{
  const int w = tlist[blockIdx.y];
  if (w < 0) return;
  const int e = w & 0xffff, mt = w >> 16;
  const int nt = blockIdx.x;
  const int cnt = counts[e];
  const int off = offsets[e];
  const int n0 = nt * 64;

  __shared__ __align__(16) ushort lds[2 * 12288];  // 48 KB

  const int tid = threadIdx.x;

  const int ra = tid >> 2, quad = tid & 3;
  const int srow = mt * 128 + ra;
  const int slotA = off + (srow < cnt ? srow : 0);
  const ushort* agp = hbuf + (size_t)slotA * INTER;
  const int q0 = quad * 2, q1 = q0 + 1;
  const int axk = ra & 7;
  const int adst0 = ra * 64 + (q0 ^ axk) * 8;
  const int adst1 = ra * 64 + (q1 ^ axk) * 8;

  const int bn = tid & 63, kg = tid >> 6;
  const float* wdp = wd + (size_t)e * (INTER * HID) + n0 + bn;
  const int bdst = bn * 64 + (kg ^ (bn & 7)) * 8;

  const int lane = tid & 63, wv = tid >> 6;
  const int wm = wv >> 1, wn = wv & 1;
  const int fr = lane & 15, ko = lane >> 4;
  const int fxk = fr & 7;

  f32x4 acc[2][2];
#pragma unroll
  for (int i = 0; i < 2; i++)
#pragma unroll
    for (int j = 0; j < 2; j++) acc[i][j] = (f32x4)(0.0f);

  uint4 pa0, pa1;
  float sb[8];

  pa0 = *(const uint4*)(agp + q0 * 8);
  pa1 = *(const uint4*)(agp + q1 * 8);
  {
    const float* p = wdp + (size_t)(kg * 8) * HID;
#pragma unroll
    for (int kk = 0; kk < 8; kk++) sb[kk] = p[(size_t)kk * HID];
  }
  {
    ushort* dA = lds;
    *(uint4*)(dA + adst0) = pa0;
    *(uint4*)(dA + adst1) = pa1;
    uint4 pb;
    pb.x = pk2(sb[0], sb[1]); pb.y = pk2(sb[2], sb[3]);
    pb.z = pk2(sb[4], sb[5]); pb.w = pk2(sb[6], sb[7]);
    *(uint4*)(dA + 8192 + bdst) = pb;
  }
  __syncthreads();

  int cbase = 0;
  for (int t = 0; t < NT_DN; ++t){
    const int nb = cbase ^ 12288;
    if (t + 1 < NT_DN){
      const int k0 = (t + 1) * 64;
      pa0 = *(const uint4*)(agp + k0 + q0 * 8);
      pa1 = *(const uint4*)(agp + k0 + q1 * 8);
      const float* p = wdp + (size_t)(k0 + kg * 8) * HID;
#pragma unroll
      for (int kk = 0; kk < 8; kk++) sb[kk] = p[(size_t)kk * HID];
    }
    const ushort* A = lds + cbase;
    const ushort* B = lds + cbase + 8192;
#pragma unroll
    for (int kk = 0; kk < 2; kk++){
      const int bsel = ((kk * 4 + ko) ^ fxk) * 8;
      bf16x8 a[2], b2[2];
#pragma unroll
      for (int mf = 0; mf < 2; mf++)
        a[mf] = *(const bf16x8*)(A + (wm * 32 + mf * 16 + fr) * 64 + bsel);
#pragma unroll
      for (int nf = 0; nf < 2; nf++)
        b2[nf] = *(const bf16x8*)(B + (wn * 32 + nf * 16 + fr) * 64 + bsel);
#pragma unroll
      for (int mf = 0; mf < 2; mf++)
#pragma unroll
        for (int nf = 0; nf < 2; nf++)
          acc[mf][nf] = __builtin_amdgcn_mfma_f32_16x16x32_bf16(a[mf], b2[nf], acc[mf][nf], 0, 0, 0);
    }
    if (t + 1 < NT_DN){
      ushort* dA = lds + nb;
      *(uint4*)(dA + adst0) = pa0;
      *(uint4*)(dA + adst1) = pa1;
      uint4 pb;
      pb.x = pk2(sb[0], sb[1]); pb.y = pk2(sb[2], sb[3]);
      pb.z = pk2(sb[4], sb[5]); pb.w = pk2(sb[6], sb[7]);
      *(uint4*)(dA + 8192 + bdst) = pb;
    }
    __syncthreads();
    cbase = nb;
  }

#pragma unroll
  for (int mf = 0; mf < 2; mf++)
#pragma unroll
    for (int j = 0; j < 4; j++){
      int rl = wm * 32 + mf * 16 + ko * 4 + j;
      int gr = mt * 128 + rl;
      if (gr < cnt){
        int tok = rows[off + gr];
        float* obase = out + (size_t)tok * HID + n0;
#pragma unroll
        for (int nf = 0; nf < 2; nf++)
          atomicAdd(obase + wn * 32 + nf * 16 + fr, acc[mf][nf][j]);
      }
    }
}

// ---------------- launch ----------------
extern "C" void kernel_launch(void* const* d_in, const int* in_sizes, int n_in,
                              void* d_out, int out_size, void* d_ws, size_t ws_size,
                              hipStream_t stream){
  const float* x  = (const float*)d_in[0];
  const float* wr = (const float*)d_in[1];
  const float* wg = (const float*)d_in[2];
  const float* wu = (const float*)d_in[3];
  const float* wd = (const float*)d_in[4];
  float* out = (float*)d_out;
  char* ws = (char*)d_ws;

  ushort* xb     = (ushort*)(ws + XB_OFF);
  ushort* hbuf   = (ushort*)(ws + HBUF_OFF);
  float*  topkw  = (float*)(ws + TKW_OFF);
  int*    topki  = (int*)(ws + TKI_OFF);
  int*    rows   = (int*)(ws + ROWS_OFF);
  float*  wts    = (float*)(ws + WTS_OFF);
  int*    offs   = (int*)(ws + OFFS_OFF);
  float*  logits = (float*)(ws + LOGIT_OFF);
  int*    counts = (int*)(ws + CNT_OFF);
  int*    fill   = (int*)(ws + FILL_OFF);
  int*    tlist  = (int*)(ws + TLIST_OFF);

  hipMemsetAsync(ws + ZERO_OFF, 0, ZERO_SZ, stream);
  hipMemsetAsync(d_out, 0, (size_t)out_size * sizeof(float), stream);

  convert_x_kernel<<<2048, 256, 0, stream>>>(x, xb);
  router_gemm<<<dim3(32, 8), 256, 0, stream>>>(x, wr, logits);
  topk_kernel<<<8, 256, 0, stream>>>(logits, topkw, topki, counts);
  prefix_kernel<<<1, 64, 0, stream>>>(counts, offs, tlist);
  scatter_kernel<<<32, 256, 0, stream>>>(topki, topkw, offs, fill, rows, wts);
  gateup_kernel<<<dim3(12, MAXT), 512, 0, stream>>>(xb, wg, wu, rows, wts, counts, offs, tlist, hbuf);
  down_kernel<<<dim3(32, MAXT), 512, 0, stream>>>(hbuf, wd, rows, counts, offs, tlist, out);
}